// Round 1
// baseline (476.413 us; speedup 1.0000x reference)
//
#include <hip/hip_runtime.h>
#include <stdint.h>

#define DMODEL 1024
#define NHEAD 16
#define HDIM 64
#define SEQ 2048
#define NBATCH 2
#define MTOK 4096  // NBATCH*SEQ

typedef float f32x4 __attribute__((ext_vector_type(4)));
typedef short s16x8 __attribute__((ext_vector_type(8)));
typedef unsigned short u16;
typedef u16 u16x4 __attribute__((ext_vector_type(4)));

typedef __attribute__((address_space(1))) const void* as1_cvp;
typedef __attribute__((address_space(3))) void* as3_vp;

__device__ inline u16 f2bf(float f) {
  uint32_t u = __float_as_uint(f);
  u = u + 0x7FFFu + ((u >> 16) & 1u);
  return (u16)(u >> 16);
}

__device__ inline void gload_lds16(const void* g, void* l) {
  __builtin_amdgcn_global_load_lds((as1_cvp)g, (as3_vp)l, 16, 0, 0);
}

// ---------------- fp32 -> bf16 convert ----------------
__global__ __launch_bounds__(256) void k_f2bf(const float* __restrict__ src,
                                              u16* __restrict__ dst, int n4) {
  int i = blockIdx.x * 256 + threadIdx.x;
  int stride = gridDim.x * 256;
  for (; i < n4; i += stride) {
    f32x4 v = ((const f32x4*)src)[i];
    u16x4 o;
    o[0] = f2bf(v[0]); o[1] = f2bf(v[1]); o[2] = f2bf(v[2]); o[3] = f2bf(v[3]);
    ((u16x4*)dst)[i] = o;
  }
}

// ---------------- bf16 GEMM: C[M,N] = A[M,K] @ B[N,K]^T + bias ----------------
// m97 structure: 128x128 tile, BK=32, 4 waves, global_load_lds width-16.
template <int OUT_BF16, int RELU>
__global__ __launch_bounds__(256) void k_gemm_bt(const u16* __restrict__ A,
                                                 const u16* __restrict__ B,
                                                 const float* __restrict__ bias,
                                                 void* __restrict__ Cv, int M,
                                                 int N, int K) {
  __shared__ alignas(16) u16 As[128 * 32];
  __shared__ alignas(16) u16 Bs[128 * 32];
  const int t = threadIdx.x;
  const int w = t >> 6;
  const int l = t & 63;
  const int brow = blockIdx.y * 128;
  const int bcol = blockIdx.x * 128;
  const int wr = (w >> 1) * 64;
  const int wc = (w & 1) * 64;

  const f32x4 Z4 = {0.f, 0.f, 0.f, 0.f};
  f32x4 acc[4][4];
  for (int m = 0; m < 4; m++)
    for (int n = 0; n < 4; n++) acc[m][n] = Z4;

  const int sr = t >> 2;        // 0..63 staging row
  const int sc = (t & 3) * 8;   // staging col (elements)
  const u16* Ab = A + (size_t)(brow + sr) * K + sc;
  const u16* Bb = B + (size_t)(bcol + sr) * K + sc;
  u16* AsW = As + w * 512;  // wave-uniform LDS base (bytes: w*1024)
  u16* BsW = Bs + w * 512;

  const int lr = l & 15;
  const int lk = (l >> 4) * 8;

  for (int k0 = 0; k0 < K; k0 += 32) {
    gload_lds16(Ab + k0, AsW);
    gload_lds16(Ab + k0 + (size_t)64 * K, AsW + 2048);
    gload_lds16(Bb + k0, BsW);
    gload_lds16(Bb + k0 + (size_t)64 * K, BsW + 2048);
    __syncthreads();
    s16x8 af[4], bf[4];
    for (int m = 0; m < 4; m++)
      af[m] = *(const s16x8*)(As + (wr + m * 16 + lr) * 32 + lk);
    for (int n = 0; n < 4; n++)
      bf[n] = *(const s16x8*)(Bs + (wc + n * 16 + lr) * 32 + lk);
    for (int m = 0; m < 4; m++)
      for (int n = 0; n < 4; n++)
        acc[m][n] = __builtin_amdgcn_mfma_f32_16x16x32_bf16(af[m], bf[n],
                                                            acc[m][n], 0, 0, 0);
    __syncthreads();
  }

  const int lg = (l >> 4) * 4;
  for (int n = 0; n < 4; n++) {
    const int col = bcol + wc + n * 16 + lr;
    const float bvv = bias ? bias[col] : 0.0f;
    for (int m = 0; m < 4; m++) {
      const int row0 = brow + wr + m * 16 + lg;
      for (int r = 0; r < 4; r++) {
        float vv = acc[m][n][r] + bvv;
        if (RELU) vv = vv > 0.f ? vv : 0.f;
        if (OUT_BF16)
          ((u16*)Cv)[(size_t)(row0 + r) * N + col] = f2bf(vv);
        else
          ((float*)Cv)[(size_t)(row0 + r) * N + col] = vv;
      }
    }
  }
}

// ---------------- causal flash attention ----------------
// grid: NBATCH*NHEAD*(SEQ/64); block 256 = 4 waves, each wave 16 q-rows.
__global__ __launch_bounds__(256) void k_attn(const u16* __restrict__ q,
                                              const u16* __restrict__ k,
                                              const u16* __restrict__ v,
                                              u16* __restrict__ o) {
  __shared__ alignas(16) u16 Qs[64 * 64];
  __shared__ alignas(16) u16 Ks[64 * 64];
  __shared__ alignas(16) u16 Vs[64 * 64];
  __shared__ alignas(16) u16 Ps[4 * 16 * 64];
  const int t = threadIdx.x;
  const int w = t >> 6;
  const int l = t & 63;
  const int qt = blockIdx.x & 31;
  const int bh = blockIdx.x >> 5;
  const int b = bh >> 4, h = bh & 15;
  const size_t base = (size_t)b * SEQ * DMODEL + h * HDIM;
  const u16* qb = q + base;
  const u16* kb = k + base;
  const u16* vb = v + base;

  // stage Q tile (64 x 64)
  {
    const int r = t >> 3;
    const int c = (t & 7) * 8;
    const u16* g0 = qb + (size_t)(qt * 64 + r) * DMODEL + c;
    gload_lds16(g0, Qs + w * 512);
    gload_lds16(g0 + (size_t)32 * DMODEL, Qs + 2048 + w * 512);
  }

  const int lr = l & 15, lg = l >> 4;
  const f32x4 Z4 = {0.f, 0.f, 0.f, 0.f};
  float m_r[4], l_r[4];
  f32x4 oacc[4];
  for (int r = 0; r < 4; r++) { m_r[r] = -3.0e38f; l_r[r] = 0.f; }
  for (int nd = 0; nd < 4; nd++) oacc[nd] = Z4;
  s16x8 aq0, aq1;

  for (int jt = 0; jt <= qt; jt++) {
    {
      const int r = t >> 3;
      const int c = (t & 7) * 8;
      const u16* g0 = kb + (size_t)(jt * 64 + r) * DMODEL + c;
      gload_lds16(g0, Ks + w * 512);
      gload_lds16(g0 + (size_t)32 * DMODEL, Ks + 2048 + w * 512);
      const u16* g1 = vb + (size_t)(jt * 64 + r) * DMODEL + c;
      gload_lds16(g1, Vs + w * 512);
      gload_lds16(g1 + (size_t)32 * DMODEL, Vs + 2048 + w * 512);
    }
    __syncthreads();
    if (jt == 0) {
      aq0 = *(const s16x8*)(Qs + (w * 16 + lr) * 64 + lg * 8);
      aq1 = *(const s16x8*)(Qs + (w * 16 + lr) * 64 + 32 + lg * 8);
    }
    // QK^T: S[16 x 64]
    f32x4 sacc[4];
    for (int n = 0; n < 4; n++) sacc[n] = Z4;
    for (int n = 0; n < 4; n++) {
      s16x8 bk0 = *(const s16x8*)(Ks + (n * 16 + lr) * 64 + lg * 8);
      s16x8 bk1 = *(const s16x8*)(Ks + (n * 16 + lr) * 64 + 32 + lg * 8);
      sacc[n] = __builtin_amdgcn_mfma_f32_16x16x32_bf16(aq0, bk0, sacc[n], 0, 0, 0);
      sacc[n] = __builtin_amdgcn_mfma_f32_16x16x32_bf16(aq1, bk1, sacc[n], 0, 0, 0);
    }
    // mask + scale + online softmax
    float p[4][4];
    float rmax[4];
    const int q0 = qt * 64 + w * 16 + lg * 4;
    const int kv0 = jt * 64 + lr;
    for (int r = 0; r < 4; r++) rmax[r] = -3.0e38f;
    for (int n = 0; n < 4; n++) {
      const int kv = kv0 + n * 16;
      for (int r = 0; r < 4; r++) {
        float sv = (kv <= q0 + r) ? sacc[n][r] * 0.125f : -1.0e20f;
        p[n][r] = sv;
        rmax[r] = fmaxf(rmax[r], sv);
      }
    }
    for (int r = 0; r < 4; r++) {
      for (int off = 8; off >= 1; off >>= 1)
        rmax[r] = fmaxf(rmax[r], __shfl_xor(rmax[r], off, 64));
      const float mn = fmaxf(m_r[r], rmax[r]);
      const float alpha = __expf(m_r[r] - mn);
      m_r[r] = mn;
      float rs = 0.f;
      for (int n = 0; n < 4; n++) {
        const float e = __expf(p[n][r] - mn);
        p[n][r] = e;
        rs += e;
      }
      for (int off = 8; off >= 1; off >>= 1) rs += __shfl_xor(rs, off, 64);
      l_r[r] = l_r[r] * alpha + rs;
      for (int nd = 0; nd < 4; nd++) oacc[nd][r] *= alpha;
    }
    // P -> LDS (wave-private)
    for (int n = 0; n < 4; n++)
      for (int r = 0; r < 4; r++)
        Ps[w * 1024 + (lg * 4 + r) * 64 + n * 16 + lr] = f2bf(p[n][r]);
    // PV
    s16x8 ap0 = *(const s16x8*)(Ps + w * 1024 + lr * 64 + lg * 8);
    s16x8 ap1 = *(const s16x8*)(Ps + w * 1024 + lr * 64 + 32 + lg * 8);
    for (int nd = 0; nd < 4; nd++) {
      s16x8 bv0, bv1;
      for (int j = 0; j < 8; j++) {
        bv0[j] = (short)Vs[(lg * 8 + j) * 64 + nd * 16 + lr];
        bv1[j] = (short)Vs[(32 + lg * 8 + j) * 64 + nd * 16 + lr];
      }
      oacc[nd] = __builtin_amdgcn_mfma_f32_16x16x32_bf16(ap0, bv0, oacc[nd], 0, 0, 0);
      oacc[nd] = __builtin_amdgcn_mfma_f32_16x16x32_bf16(ap1, bv1, oacc[nd], 0, 0, 0);
    }
    __syncthreads();
  }
  for (int nd = 0; nd < 4; nd++) {
    for (int r = 0; r < 4; r++) {
      const int row = qt * 64 + w * 16 + lg * 4 + r;
      const float val = oacc[nd][r] / l_r[r];
      o[(size_t)(b * SEQ + row) * DMODEL + h * HDIM + nd * 16 + lr] = f2bf(val);
    }
  }
}

// ---------------- fused residual add + LayerNorm ----------------
__global__ __launch_bounds__(256) void k_add_ln(const float* __restrict__ X,
                                                const float* __restrict__ Y,
                                                const float* __restrict__ w,
                                                const float* __restrict__ bias,
                                                float* __restrict__ of32,
                                                u16* __restrict__ obf) {
  __shared__ float sred[4];
  const int t = threadIdx.x;
  const size_t row = blockIdx.x;
  f32x4 xv = ((const f32x4*)(X + row * DMODEL))[t];
  f32x4 yv = ((const f32x4*)(Y + row * DMODEL))[t];
  f32x4 vv;
  for (int i = 0; i < 4; i++) vv[i] = xv[i] + yv[i];
  float s = vv[0] + vv[1] + vv[2] + vv[3];
  for (int off = 32; off >= 1; off >>= 1) s += __shfl_xor(s, off, 64);
  if ((t & 63) == 0) sred[t >> 6] = s;
  __syncthreads();
  s = sred[0] + sred[1] + sred[2] + sred[3];
  const float mean = s * (1.0f / DMODEL);
  f32x4 dv;
  for (int i = 0; i < 4; i++) dv[i] = vv[i] - mean;
  float ss = dv[0] * dv[0] + dv[1] * dv[1] + dv[2] * dv[2] + dv[3] * dv[3];
  __syncthreads();
  for (int off = 32; off >= 1; off >>= 1) ss += __shfl_xor(ss, off, 64);
  if ((t & 63) == 0) sred[t >> 6] = ss;
  __syncthreads();
  ss = sred[0] + sred[1] + sred[2] + sred[3];
  const float rs = rsqrtf(ss * (1.0f / DMODEL) + 1e-5f);
  f32x4 wv = ((const f32x4*)w)[t];
  f32x4 bv = ((const f32x4*)bias)[t];
  f32x4 ov;
  for (int i = 0; i < 4; i++) ov[i] = dv[i] * rs * wv[i] + bv[i];
  if (of32) ((f32x4*)(of32 + row * DMODEL))[t] = ov;
  if (obf) {
    u16x4 ob;
    for (int i = 0; i < 4; i++) ob[i] = f2bf(ov[i]);
    ((u16x4*)(obf + row * DMODEL))[t] = ob;
  }
}

extern "C" void kernel_launch(void* const* d_in, const int* in_sizes, int n_in,
                              void* d_out, int out_size, void* d_ws,
                              size_t ws_size, hipStream_t stream) {
  const float* X = (const float*)d_in[0];
  const float* Wq = (const float*)d_in[1];
  const float* bq = (const float*)d_in[2];
  const float* Wk = (const float*)d_in[3];
  const float* bk = (const float*)d_in[4];
  const float* Wv = (const float*)d_in[5];
  const float* bvp = (const float*)d_in[6];
  const float* Wo = (const float*)d_in[7];
  const float* bo = (const float*)d_in[8];
  const float* ln1w = (const float*)d_in[9];
  const float* ln1b = (const float*)d_in[10];
  const float* Wup = (const float*)d_in[11];
  const float* bup = (const float*)d_in[12];
  const float* Wdown = (const float*)d_in[13];
  const float* bdown = (const float*)d_in[14];
  const float* ln2w = (const float*)d_in[15];
  const float* ln2b = (const float*)d_in[16];

  char* ws = (char*)d_ws;
  const size_t MB = 1024 * 1024;
  u16* Xbf = (u16*)(ws + 0);          // 8MB, dead after QKV
  u16* qbf = (u16*)(ws + 8 * MB);     // 8MB
  u16* kbf = (u16*)(ws + 16 * MB);    // 8MB
  u16* vbf = (u16*)(ws + 24 * MB);    // 8MB
  u16* wbuf = (u16*)(ws + 32 * MB);   // 8MB weight scratch
  u16* attnb = (u16*)(ws + 40 * MB);  // 8MB
  float* Ybuf = (float*)(ws + 48 * MB);  // 16MB (Yo then Ydown)
  float* xres = (float*)(ws + 64 * MB);  // 16MB
  u16* xbf = (u16*)(ws + 80 * MB);       // 8MB
  u16* upbf = (u16*)(ws + 0);            // 32MB reuse (0..32MB)

  const dim3 blk(256);
  // converts
  k_f2bf<<<2048, blk, 0, stream>>>(X, Xbf, (MTOK * DMODEL) / 4);
  k_f2bf<<<512, blk, 0, stream>>>(Wq, wbuf + 0 * 1024 * 1024, (DMODEL * DMODEL) / 4);
  k_f2bf<<<512, blk, 0, stream>>>(Wk, wbuf + 1 * 1024 * 1024, (DMODEL * DMODEL) / 4);
  k_f2bf<<<512, blk, 0, stream>>>(Wv, wbuf + 2 * 1024 * 1024, (DMODEL * DMODEL) / 4);
  k_f2bf<<<512, blk, 0, stream>>>(Wo, wbuf + 3 * 1024 * 1024, (DMODEL * DMODEL) / 4);

  const dim3 g1(DMODEL / 128, MTOK / 128);  // (8, 32)
  k_gemm_bt<1, 0><<<g1, blk, 0, stream>>>(Xbf, wbuf + 0 * 1024 * 1024, bq, qbf,
                                          MTOK, DMODEL, DMODEL);
  k_gemm_bt<1, 0><<<g1, blk, 0, stream>>>(Xbf, wbuf + 1 * 1024 * 1024, bk, kbf,
                                          MTOK, DMODEL, DMODEL);
  k_gemm_bt<1, 0><<<g1, blk, 0, stream>>>(Xbf, wbuf + 2 * 1024 * 1024, bvp, vbf,
                                          MTOK, DMODEL, DMODEL);
  k_attn<<<NBATCH * NHEAD * (SEQ / 64), blk, 0, stream>>>(qbf, kbf, vbf, attnb);
  k_gemm_bt<0, 0><<<g1, blk, 0, stream>>>(attnb, wbuf + 3 * 1024 * 1024, bo,
                                          Ybuf, MTOK, DMODEL, DMODEL);
  k_add_ln<<<MTOK, blk, 0, stream>>>(X, Ybuf, ln1w, ln1b, xres, xbf);

  k_f2bf<<<2048, blk, 0, stream>>>(Wup, wbuf, (4 * DMODEL * DMODEL) / 4);
  const dim3 g2((4 * DMODEL) / 128, MTOK / 128);  // (32, 32)
  k_gemm_bt<1, 1><<<g2, blk, 0, stream>>>(xbf, wbuf, bup, upbf, MTOK, 4 * DMODEL,
                                          DMODEL);
  k_f2bf<<<2048, blk, 0, stream>>>(Wdown, wbuf, (4 * DMODEL * DMODEL) / 4);
  const dim3 g3(DMODEL / 128, MTOK / 128);  // (8, 32)
  k_gemm_bt<0, 0><<<g3, blk, 0, stream>>>(upbf, wbuf, bdown, Ybuf, MTOK, DMODEL,
                                          4 * DMODEL);
  k_add_ln<<<MTOK, blk, 0, stream>>>(xres, Ybuf, ln2w, ln2b, (float*)d_out,
                                     (u16*)nullptr);
}

// Round 2
// 398.406 us; speedup vs baseline: 1.1958x; 1.1958x over previous
//
#include <hip/hip_runtime.h>
#include <stdint.h>

#define DMODEL 1024
#define NHEAD 16
#define HDIM 64
#define SEQ 2048
#define NBATCH 2
#define MTOK 4096  // NBATCH*SEQ

typedef float f32x4 __attribute__((ext_vector_type(4)));
typedef short s16x8 __attribute__((ext_vector_type(8)));
typedef unsigned short u16;
typedef u16 u16x4 __attribute__((ext_vector_type(4)));

typedef __attribute__((address_space(1))) const void* as1_cvp;
typedef __attribute__((address_space(3))) void* as3_vp;

__device__ inline u16 f2bf(float f) {
  uint32_t u = __float_as_uint(f);
  u = u + 0x7FFFu + ((u >> 16) & 1u);
  return (u16)(u >> 16);
}

__device__ inline void gload_lds16(const void* g, void* l) {
  __builtin_amdgcn_global_load_lds((as1_cvp)g, (as3_vp)l, 16, 0, 0);
}

// ---------------- fp32 -> bf16 convert ----------------
__global__ __launch_bounds__(256) void k_f2bf(const float* __restrict__ src,
                                              u16* __restrict__ dst, int n4) {
  int i = blockIdx.x * 256 + threadIdx.x;
  int stride = gridDim.x * 256;
  for (; i < n4; i += stride) {
    f32x4 v = ((const f32x4*)src)[i];
    u16x4 o;
    o[0] = f2bf(v[0]); o[1] = f2bf(v[1]); o[2] = f2bf(v[2]); o[3] = f2bf(v[3]);
    ((u16x4*)dst)[i] = o;
  }
}

// ---------------- bf16 GEMM: C[M,N] = A[M,K] @ B[N,K]^T + bias ----------------
// m97 structure: 128x128 tile, BK=32, 4 waves, global_load_lds width-16.
// MODE: 0 = f32 out, 1 = bf16 out, 2 = bf16 out + relu
template <int MODE>
__global__ __launch_bounds__(256) void k_gemm_bt(const u16* __restrict__ A,
                                                 const u16* __restrict__ B,
                                                 const float* __restrict__ bias,
                                                 void* __restrict__ Cv, int M,
                                                 int N, int K) {
  __shared__ alignas(16) u16 As[128 * 32];
  __shared__ alignas(16) u16 Bs[128 * 32];
  const int t = threadIdx.x;
  const int w = t >> 6;
  const int l = t & 63;
  const int brow = blockIdx.y * 128;
  const int bcol = blockIdx.x * 128;
  const int wr = (w >> 1) * 64;
  const int wc = (w & 1) * 64;

  const f32x4 Z4 = {0.f, 0.f, 0.f, 0.f};
  f32x4 acc[4][4];
  for (int m = 0; m < 4; m++)
    for (int n = 0; n < 4; n++) acc[m][n] = Z4;

  const int sr = t >> 2;        // 0..63 staging row
  const int sc = (t & 3) * 8;   // staging col (elements)
  const u16* Ab = A + (size_t)(brow + sr) * K + sc;
  const u16* Bb = B + (size_t)(bcol + sr) * K + sc;
  u16* AsW = As + w * 512;  // wave-uniform LDS base (bytes: w*1024)
  u16* BsW = Bs + w * 512;

  const int lr = l & 15;
  const int lk = (l >> 4) * 8;

  for (int k0 = 0; k0 < K; k0 += 32) {
    gload_lds16(Ab + k0, AsW);
    gload_lds16(Ab + k0 + (size_t)64 * K, AsW + 2048);
    gload_lds16(Bb + k0, BsW);
    gload_lds16(Bb + k0 + (size_t)64 * K, BsW + 2048);
    __syncthreads();
    s16x8 af[4], bf[4];
    for (int m = 0; m < 4; m++)
      af[m] = *(const s16x8*)(As + (wr + m * 16 + lr) * 32 + lk);
    for (int n = 0; n < 4; n++)
      bf[n] = *(const s16x8*)(Bs + (wc + n * 16 + lr) * 32 + lk);
    for (int m = 0; m < 4; m++)
      for (int n = 0; n < 4; n++)
        acc[m][n] = __builtin_amdgcn_mfma_f32_16x16x32_bf16(af[m], bf[n],
                                                            acc[m][n], 0, 0, 0);
    __syncthreads();
  }

  const int lg = (l >> 4) * 4;
  for (int n = 0; n < 4; n++) {
    const int col = bcol + wc + n * 16 + lr;
    const float bvv = bias ? bias[col] : 0.0f;
    for (int m = 0; m < 4; m++) {
      const int row0 = brow + wr + m * 16 + lg;
      for (int r = 0; r < 4; r++) {
        float vv = acc[m][n][r] + bvv;
        if (MODE == 2) vv = vv > 0.f ? vv : 0.f;
        if (MODE != 0)
          ((u16*)Cv)[(size_t)(row0 + r) * N + col] = f2bf(vv);
        else
          ((float*)Cv)[(size_t)(row0 + r) * N + col] = vv;
      }
    }
  }
}

// ---------------- fused QKV GEMM ----------------
// C[M, 3072] = X @ [Wq;Wk;Wv]^T. Epilogue routes by col region:
//  Q: qbf[tok][ck] plain
//  K: kbf[tok][h*64 + dswz]  (d-chunk XOR tok&7)
//  V: vtbf[b][h][d][s_swz]   (s-chunk XOR d&7), i.e. transposed
__global__ __launch_bounds__(256) void k_gemm_qkv(
    const u16* __restrict__ A, const u16* __restrict__ B,
    const float* __restrict__ bq, const float* __restrict__ bk,
    const float* __restrict__ bv, u16* __restrict__ qbf, u16* __restrict__ kbf,
    u16* __restrict__ vtbf, int M, int N, int K) {
  __shared__ alignas(16) u16 As[128 * 32];
  __shared__ alignas(16) u16 Bs[128 * 32];
  const int t = threadIdx.x;
  const int w = t >> 6;
  const int l = t & 63;
  const int brow = blockIdx.y * 128;
  const int bcol = blockIdx.x * 128;
  const int wr = (w >> 1) * 64;
  const int wc = (w & 1) * 64;

  const f32x4 Z4 = {0.f, 0.f, 0.f, 0.f};
  f32x4 acc[4][4];
  for (int m = 0; m < 4; m++)
    for (int n = 0; n < 4; n++) acc[m][n] = Z4;

  const int sr = t >> 2;
  const int sc = (t & 3) * 8;
  const u16* Ab = A + (size_t)(brow + sr) * K + sc;
  const u16* Bb = B + (size_t)(bcol + sr) * K + sc;
  u16* AsW = As + w * 512;
  u16* BsW = Bs + w * 512;

  const int lr = l & 15;
  const int lk = (l >> 4) * 8;

  for (int k0 = 0; k0 < K; k0 += 32) {
    gload_lds16(Ab + k0, AsW);
    gload_lds16(Ab + k0 + (size_t)64 * K, AsW + 2048);
    gload_lds16(Bb + k0, BsW);
    gload_lds16(Bb + k0 + (size_t)64 * K, BsW + 2048);
    __syncthreads();
    s16x8 af[4], bf[4];
    for (int m = 0; m < 4; m++)
      af[m] = *(const s16x8*)(As + (wr + m * 16 + lr) * 32 + lk);
    for (int n = 0; n < 4; n++)
      bf[n] = *(const s16x8*)(Bs + (wc + n * 16 + lr) * 32 + lk);
    for (int m = 0; m < 4; m++)
      for (int n = 0; n < 4; n++)
        acc[m][n] = __builtin_amdgcn_mfma_f32_16x16x32_bf16(af[m], bf[n],
                                                            acc[m][n], 0, 0, 0);
    __syncthreads();
  }

  const int lg = (l >> 4) * 4;
  for (int n = 0; n < 4; n++) {
    const int col = bcol + wc + n * 16 + lr;
    const int region = col >> 10;  // block-uniform (128 | 1024)
    const int ck = col & 1023;
    const int h = ck >> 6, d = ck & 63;
    const float bvv = region == 0 ? bq[ck] : region == 1 ? bk[ck] : bv[ck];
    for (int m = 0; m < 4; m++) {
      const int row0 = brow + wr + m * 16 + lg;
      for (int r = 0; r < 4; r++) {
        const int tok = row0 + r;
        const u16 bfv = f2bf(acc[m][n][r] + bvv);
        if (region == 0) {
          qbf[(size_t)tok * 1024 + ck] = bfv;
        } else if (region == 1) {
          const int dd = ((((d >> 3) ^ tok) & 7) << 3) | (d & 7);
          kbf[(size_t)tok * 1024 + (h << 6) + dd] = bfv;
        } else {
          const int b = tok >> 11, s = tok & 2047;
          const int ss = (s & ~63) | (((((s >> 3) ^ d) & 7)) << 3) | (s & 7);
          vtbf[((size_t)((b << 4) + h) * 64 + d) * 2048 + ss] = bfv;
        }
      }
    }
  }
}

// ---------------- causal flash attention ----------------
// grid: NBATCH*NHEAD*(SEQ/64); block 256 = 4 waves, each wave 16 q-rows.
// K in kbf is d-chunk-swizzled per token; V in vtbf is [b][h][d][s] with
// s-chunk-swizzled rows. All B-fragment reads are conflict-free b128.
__global__ __launch_bounds__(256) void k_attn(const u16* __restrict__ q,
                                              const u16* __restrict__ kk,
                                              const u16* __restrict__ vt,
                                              u16* __restrict__ o) {
  __shared__ alignas(16) u16 Qs[64 * 64];
  __shared__ alignas(16) u16 Ks[64 * 64];
  __shared__ alignas(16) u16 Vs[64 * 64];
  __shared__ alignas(16) u16 Ps[4 * 16 * 64];
  const int t = threadIdx.x;
  const int w = t >> 6;
  const int l = t & 63;
  const int i = blockIdx.x & 31;
  const int qt = (i & 1) ? (31 - (i >> 1)) : (i >> 1);  // balance causal tail
  const int bh = blockIdx.x >> 5;
  const int b = bh >> 4, h = bh & 15;
  const u16* qb = q + (size_t)b * SEQ * DMODEL + h * HDIM;
  const u16* kb = kk + (size_t)b * SEQ * DMODEL + h * HDIM;
  const u16* vb = vt + (size_t)((b * 16 + h) * 64) * SEQ;

  const int sr = t >> 3;        // 0..31
  const int sc = (t & 7) * 8;   // chunk col
  // stage Q tile (64 x 64)
  gload_lds16(qb + (size_t)(qt * 64 + sr) * DMODEL + sc, Qs + w * 512);
  gload_lds16(qb + (size_t)(qt * 64 + sr + 32) * DMODEL + sc,
              Qs + 2048 + w * 512);

  const int lr = l & 15, lg = l >> 4;
  const int key = lr & 7;
  const f32x4 Z4 = {0.f, 0.f, 0.f, 0.f};
  float m_r[4], l_r[4];
  f32x4 oacc[4];
  for (int r = 0; r < 4; r++) { m_r[r] = -3.0e38f; l_r[r] = 0.f; }
  for (int nd = 0; nd < 4; nd++) oacc[nd] = Z4;
  s16x8 aq0, aq1;

  for (int jt = 0; jt <= qt; jt++) {
    gload_lds16(kb + (size_t)(jt * 64 + sr) * DMODEL + sc, Ks + w * 512);
    gload_lds16(kb + (size_t)(jt * 64 + sr + 32) * DMODEL + sc,
                Ks + 2048 + w * 512);
    gload_lds16(vb + (size_t)sr * SEQ + jt * 64 + sc, Vs + w * 512);
    gload_lds16(vb + (size_t)(sr + 32) * SEQ + jt * 64 + sc,
                Vs + 2048 + w * 512);
    __syncthreads();
    if (jt == 0) {
      aq0 = *(const s16x8*)(Qs + (w * 16 + lr) * 64 + lg * 8);
      aq1 = *(const s16x8*)(Qs + (w * 16 + lr) * 64 + 32 + lg * 8);
    }
    // QK^T: S[16 x 64], swizzle-decoded conflict-free b128 reads
    f32x4 sacc[4];
    for (int n = 0; n < 4; n++) sacc[n] = Z4;
    for (int n = 0; n < 4; n++) {
      const int kr = n * 16 + lr;
      s16x8 bk0 = *(const s16x8*)(Ks + kr * 64 + ((lg ^ key) << 3));
      s16x8 bk1 = *(const s16x8*)(Ks + kr * 64 + (((4 + lg) ^ key) << 3));
      sacc[n] = __builtin_amdgcn_mfma_f32_16x16x32_bf16(aq0, bk0, sacc[n], 0, 0, 0);
      sacc[n] = __builtin_amdgcn_mfma_f32_16x16x32_bf16(aq1, bk1, sacc[n], 0, 0, 0);
    }
    // mask + scale + online softmax
    float p[4][4];
    float rmax[4];
    const int q0 = qt * 64 + w * 16 + lg * 4;
    const int kv0 = jt * 64 + lr;
    for (int r = 0; r < 4; r++) rmax[r] = -3.0e38f;
    for (int n = 0; n < 4; n++) {
      const int kv = kv0 + n * 16;
      for (int r = 0; r < 4; r++) {
        float sv = (kv <= q0 + r) ? sacc[n][r] * 0.125f : -1.0e20f;
        p[n][r] = sv;
        rmax[r] = fmaxf(rmax[r], sv);
      }
    }
    for (int r = 0; r < 4; r++) {
      for (int off = 8; off >= 1; off >>= 1)
        rmax[r] = fmaxf(rmax[r], __shfl_xor(rmax[r], off, 64));
      const float mn = fmaxf(m_r[r], rmax[r]);
      const float alpha = __expf(m_r[r] - mn);
      m_r[r] = mn;
      float rs = 0.f;
      for (int n = 0; n < 4; n++) {
        const float e = __expf(p[n][r] - mn);
        p[n][r] = e;
        rs += e;
      }
      for (int off = 8; off >= 1; off >>= 1) rs += __shfl_xor(rs, off, 64);
      l_r[r] = l_r[r] * alpha + rs;
      for (int nd = 0; nd < 4; nd++) oacc[nd][r] *= alpha;
    }
    // P -> LDS (wave-private), chunk-swizzled by q-row
    for (int n = 0; n < 4; n++)
      for (int r = 0; r < 4; r++) {
        const int qq = lg * 4 + r;
        const int chunk = (n << 1) | (lr >> 3);
        Ps[w * 1024 + qq * 64 + (((chunk ^ qq) & 7) << 3) + (lr & 7)] =
            f2bf(p[n][r]);
      }
    // PV: A = P (swizzle-decoded), B = Vt rows (swizzle-decoded)
    s16x8 ap0 = *(const s16x8*)(Ps + w * 1024 + lr * 64 + ((lg ^ key) << 3));
    s16x8 ap1 =
        *(const s16x8*)(Ps + w * 1024 + lr * 64 + (((4 + lg) ^ key) << 3));
    for (int nd = 0; nd < 4; nd++) {
      const int dr = nd * 16 + lr;
      s16x8 bv0 = *(const s16x8*)(Vs + dr * 64 + ((lg ^ key) << 3));
      s16x8 bv1 = *(const s16x8*)(Vs + dr * 64 + (((4 + lg) ^ key) << 3));
      oacc[nd] = __builtin_amdgcn_mfma_f32_16x16x32_bf16(ap0, bv0, oacc[nd], 0, 0, 0);
      oacc[nd] = __builtin_amdgcn_mfma_f32_16x16x32_bf16(ap1, bv1, oacc[nd], 0, 0, 0);
    }
    __syncthreads();
  }
  for (int nd = 0; nd < 4; nd++) {
    for (int r = 0; r < 4; r++) {
      const int row = qt * 64 + w * 16 + lg * 4 + r;
      const float val = oacc[nd][r] / l_r[r];
      o[(size_t)(b * SEQ + row) * DMODEL + h * HDIM + nd * 16 + lr] = f2bf(val);
    }
  }
}

// ---------------- fused residual add + LayerNorm ----------------
__global__ __launch_bounds__(256) void k_add_ln(const float* __restrict__ X,
                                                const float* __restrict__ Y,
                                                const float* __restrict__ w,
                                                const float* __restrict__ bias,
                                                float* __restrict__ of32,
                                                u16* __restrict__ obf) {
  __shared__ float sred[4];
  const int t = threadIdx.x;
  const size_t row = blockIdx.x;
  f32x4 xv = ((const f32x4*)(X + row * DMODEL))[t];
  f32x4 yv = ((const f32x4*)(Y + row * DMODEL))[t];
  f32x4 vv;
  for (int i = 0; i < 4; i++) vv[i] = xv[i] + yv[i];
  float s = vv[0] + vv[1] + vv[2] + vv[3];
  for (int off = 32; off >= 1; off >>= 1) s += __shfl_xor(s, off, 64);
  if ((t & 63) == 0) sred[t >> 6] = s;
  __syncthreads();
  s = sred[0] + sred[1] + sred[2] + sred[3];
  const float mean = s * (1.0f / DMODEL);
  f32x4 dv;
  for (int i = 0; i < 4; i++) dv[i] = vv[i] - mean;
  float ss = dv[0] * dv[0] + dv[1] * dv[1] + dv[2] * dv[2] + dv[3] * dv[3];
  __syncthreads();
  for (int off = 32; off >= 1; off >>= 1) ss += __shfl_xor(ss, off, 64);
  if ((t & 63) == 0) sred[t >> 6] = ss;
  __syncthreads();
  ss = sred[0] + sred[1] + sred[2] + sred[3];
  const float rs = rsqrtf(ss * (1.0f / DMODEL) + 1e-5f);
  f32x4 wv = ((const f32x4*)w)[t];
  f32x4 bv = ((const f32x4*)bias)[t];
  f32x4 ov;
  for (int i = 0; i < 4; i++) ov[i] = dv[i] * rs * wv[i] + bv[i];
  if (of32) ((f32x4*)(of32 + row * DMODEL))[t] = ov;
  if (obf) {
    u16x4 ob;
    for (int i = 0; i < 4; i++) ob[i] = f2bf(ov[i]);
    ((u16x4*)(obf + row * DMODEL))[t] = ob;
  }
}

extern "C" void kernel_launch(void* const* d_in, const int* in_sizes, int n_in,
                              void* d_out, int out_size, void* d_ws,
                              size_t ws_size, hipStream_t stream) {
  const float* X = (const float*)d_in[0];
  const float* Wq = (const float*)d_in[1];
  const float* bq = (const float*)d_in[2];
  const float* Wk = (const float*)d_in[3];
  const float* bk = (const float*)d_in[4];
  const float* Wv = (const float*)d_in[5];
  const float* bvp = (const float*)d_in[6];
  const float* Wo = (const float*)d_in[7];
  const float* bo = (const float*)d_in[8];
  const float* ln1w = (const float*)d_in[9];
  const float* ln1b = (const float*)d_in[10];
  const float* Wup = (const float*)d_in[11];
  const float* bup = (const float*)d_in[12];
  const float* Wdown = (const float*)d_in[13];
  const float* bdown = (const float*)d_in[14];
  const float* ln2w = (const float*)d_in[15];
  const float* ln2b = (const float*)d_in[16];

  char* ws = (char*)d_ws;
  const size_t MB = 1024 * 1024;
  u16* Xbf = (u16*)(ws + 0);          // 8MB, dead after QKV GEMM
  u16* qbf = (u16*)(ws + 8 * MB);     // 8MB
  u16* kbf = (u16*)(ws + 16 * MB);    // 8MB (d-swizzled)
  u16* vtbf = (u16*)(ws + 24 * MB);   // 8MB (transposed + s-swizzled)
  u16* wqkv = (u16*)(ws + 32 * MB);   // 6MB concat [Wq;Wk;Wv] bf16
  u16* wo = (u16*)(ws + 38 * MB);     // 2MB
  u16* attnb = (u16*)(ws + 40 * MB);  // 8MB
  float* Ybuf = (float*)(ws + 48 * MB);  // 16MB
  float* xres = (float*)(ws + 64 * MB);  // 16MB
  u16* xbf = (u16*)(ws + 80 * MB);       // 8MB
  u16* upbf = (u16*)(ws + 0);            // 32MB reuse (0..32MB)
  u16* wbig = (u16*)(ws + 32 * MB);      // 8MB (Wup/Wdown bf16, reuse)

  const dim3 blk(256);
  // converts
  k_f2bf<<<2048, blk, 0, stream>>>(X, Xbf, (MTOK * DMODEL) / 4);
  k_f2bf<<<512, blk, 0, stream>>>(Wq, wqkv + 0 * 1024 * 1024, (DMODEL * DMODEL) / 4);
  k_f2bf<<<512, blk, 0, stream>>>(Wk, wqkv + 1 * 1024 * 1024, (DMODEL * DMODEL) / 4);
  k_f2bf<<<512, blk, 0, stream>>>(Wv, wqkv + 2 * 1024 * 1024, (DMODEL * DMODEL) / 4);
  k_f2bf<<<512, blk, 0, stream>>>(Wo, wo, (DMODEL * DMODEL) / 4);

  const dim3 gqkv(3 * DMODEL / 128, MTOK / 128);  // (24, 32)
  k_gemm_qkv<<<gqkv, blk, 0, stream>>>(Xbf, wqkv, bq, bk, bvp, qbf, kbf, vtbf,
                                       MTOK, 3 * DMODEL, DMODEL);
  k_attn<<<NBATCH * NHEAD * (SEQ / 64), blk, 0, stream>>>(qbf, kbf, vtbf, attnb);
  const dim3 g1(DMODEL / 128, MTOK / 128);  // (8, 32)
  k_gemm_bt<0><<<g1, blk, 0, stream>>>(attnb, wo, bo, Ybuf, MTOK, DMODEL,
                                       DMODEL);
  k_add_ln<<<MTOK, blk, 0, stream>>>(X, Ybuf, ln1w, ln1b, xres, xbf);

  k_f2bf<<<2048, blk, 0, stream>>>(Wup, wbig, (4 * DMODEL * DMODEL) / 4);
  const dim3 g2((4 * DMODEL) / 128, MTOK / 128);  // (32, 32)
  k_gemm_bt<2><<<g2, blk, 0, stream>>>(xbf, wbig, bup, upbf, MTOK, 4 * DMODEL,
                                       DMODEL);
  k_f2bf<<<2048, blk, 0, stream>>>(Wdown, wbig, (4 * DMODEL * DMODEL) / 4);
  k_gemm_bt<0><<<g1, blk, 0, stream>>>(upbf, wbig, bdown, Ybuf, MTOK, DMODEL,
                                       4 * DMODEL);
  k_add_ln<<<MTOK, blk, 0, stream>>>(xres, Ybuf, ln2w, ln2b, (float*)d_out,
                                     (u16*)nullptr);
}